// Round 7
// baseline (688.580 us; speedup 1.0000x reference)
//
#include <hip/hip_runtime.h>

#define N_NODES   50000
#define N_EDGES   600000
#define HID       128
#define N_GRAPHS  128
#define N_CLASSES 5
#define SCAN_BLK  ((N_NODES + 255) / 256)   // 196

// --- degree (in-degree by dst, excluding self-loops) ---
__global__ void k_deg(const int* __restrict__ dst, int* __restrict__ ideg, int E) {
    int i = blockIdx.x * blockDim.x + threadIdx.x;
    if (i < E) atomicAdd(&ideg[dst[i]], 1);
}

// --- 3-phase hierarchical scan of ideg -> row_start[0..n]; dis fused into phase 1 ---
__global__ void k_scan_part(const int* __restrict__ ideg, int* __restrict__ bsum,
                            float* __restrict__ dis, int n) {
    __shared__ int s[256];
    int t = threadIdx.x;
    int i = blockIdx.x * 256 + t;
    int v = (i < n) ? ideg[i] : 0;
    if (i < n) dis[i] = 1.0f / sqrtf((float)v + 1.0f);
    s[t] = v;
    __syncthreads();
    for (int off = 128; off > 0; off >>= 1) {
        if (t < off) s[t] += s[t + off];
        __syncthreads();
    }
    if (t == 0) bsum[blockIdx.x] = s[0];
}

__global__ void k_scan_bsum(const int* __restrict__ bsum, int* __restrict__ boff, int B) {
    __shared__ int s[256];
    int t = threadIdx.x;
    int v = (t < B) ? bsum[t] : 0;
    s[t] = v;
    __syncthreads();
    for (int off = 1; off < 256; off <<= 1) {
        int u = (t >= off) ? s[t - off] : 0;
        __syncthreads();
        s[t] += u;
        __syncthreads();
    }
    if (t < B) boff[t] = s[t] - v;
    if (t == 255) boff[B] = s[255];  // grand total
}

__global__ void k_scan_write(const int* __restrict__ ideg, const int* __restrict__ boff,
                             int* __restrict__ row_start, int n, int B) {
    __shared__ int s[256];
    int t = threadIdx.x;
    int i = blockIdx.x * 256 + t;
    int v = (i < n) ? ideg[i] : 0;
    s[t] = v;
    __syncthreads();
    for (int off = 1; off < 256; off <<= 1) {
        int u = (t >= off) ? s[t - off] : 0;
        __syncthreads();
        s[t] += u;
        __syncthreads();
    }
    if (i < n) row_start[i] = boff[blockIdx.x] + s[t] - v;
    if (blockIdx.x == 0 && t == 0) row_start[n] = boff[B];
}

// --- CSR fill: col[] holds src of each incoming edge, grouped by dst ---
__global__ void k_fill(const int* __restrict__ src, const int* __restrict__ dst,
                       const int* __restrict__ row_start, int* __restrict__ cursor,
                       int* __restrict__ col, int E) {
    int i = blockIdx.x * blockDim.x + threadIdx.x;
    if (i < E) {
        int d = dst[i];
        int pos = atomicAdd(&cursor[d], 1);
        col[row_start[d] + pos] = src[i];
    }
}

// --- graph node counts via binary search on sorted batch ---
__global__ void k_goff(const int* __restrict__ batch, int* __restrict__ gcnt, int n) {
    __shared__ int s[N_GRAPHS + 1];
    int t = threadIdx.x;
    if (t <= N_GRAPHS) {
        int lo = 0, hi = n;
        while (lo < hi) {
            int mid = (lo + hi) >> 1;
            if (batch[mid] < t) lo = mid + 1; else hi = mid;
        }
        s[t] = lo;
    }
    __syncthreads();
    if (t < N_GRAPHS) gcnt[t] = s[t + 1] - s[t];
}

// --- layer-1 GEMM with dis pre-scale, float4 output: out[i,:] = dis[i] * (x@W1)[i,:] ---
__global__ void k_gemm_in(const float* __restrict__ x, const float* __restrict__ W,
                          const float* __restrict__ dis, float* __restrict__ out, int n) {
    int idx = blockIdx.x * blockDim.x + threadIdx.x;  // n*32 threads, 4 cols each
    if (idx >= n * 32) return;
    int row = idx >> 5, c4 = (idx & 31) * 4;
    float x0 = x[row * 3 + 0], x1 = x[row * 3 + 1], x2 = x[row * 3 + 2];
    float4 w0 = *(const float4*)&W[0 * HID + c4];
    float4 w1 = *(const float4*)&W[1 * HID + c4];
    float4 w2 = *(const float4*)&W[2 * HID + c4];
    float dd = dis[row];
    float4 o;
    o.x = dd * fmaf(x2, w2.x, fmaf(x1, w1.x, x0 * w0.x));
    o.y = dd * fmaf(x2, w2.y, fmaf(x1, w1.y, x0 * w0.y));
    o.z = dd * fmaf(x2, w2.z, fmaf(x1, w1.z, x0 * w0.z));
    o.w = dd * fmaf(x2, w2.w, fmaf(x1, w1.w, x0 * w0.w));
    *(float4*)&out[(size_t)row * HID + c4] = o;
}

// === fused aggregate + ReLU + next-layer GEMM ===
// Per wave (1 dst): z[d,:] = relu(dd * (t[d]+sum_{s in N(d)} t[s]) + b)   [phase A]
// then tn[d,:] = dd' * (z[d,:] @ Wn)  via wave-private LDS broadcast      [phase B]
// Phase B's FMA stream fills the issue slots phase A leaves idle (VALUBusy 19%).
__global__ __launch_bounds__(256) void k_agg_gemm(const float* __restrict__ t,
                                                  const float* __restrict__ dis,
                                                  const int* __restrict__ row_start,
                                                  const int* __restrict__ col,
                                                  const float* __restrict__ bias,
                                                  const float* __restrict__ Wn,
                                                  float* __restrict__ tn) {
    __shared__ float zs[4][HID];
    int lane = threadIdx.x & 63;
    int wid  = threadIdx.x >> 6;
    int d = blockIdx.x * 4 + wid;
    if (d >= N_NODES) return;  // no barriers below; wave-uniform exit is safe
    const float2* t2 = (const float2*)t;
    float2 bv = ((const float2*)bias)[lane];
    float dd = dis[d];
    int j0 = row_start[d], j1 = row_start[d + 1];
    float2 self = t2[(size_t)d * 64 + lane];
    float ax0 = self.x, ay0 = self.y;
    float ax1 = 0.f, ay1 = 0.f, ax2 = 0.f, ay2 = 0.f, ax3 = 0.f, ay3 = 0.f;
    int j = j0;
    for (; j + 3 < j1; j += 4) {
        int s0 = col[j], s1 = col[j + 1], s2 = col[j + 2], s3 = col[j + 3];
        float2 v0 = t2[(size_t)s0 * 64 + lane];
        float2 v1 = t2[(size_t)s1 * 64 + lane];
        float2 v2 = t2[(size_t)s2 * 64 + lane];
        float2 v3 = t2[(size_t)s3 * 64 + lane];
        ax0 += v0.x; ay0 += v0.y;
        ax1 += v1.x; ay1 += v1.y;
        ax2 += v2.x; ay2 += v2.y;
        ax3 += v3.x; ay3 += v3.y;
    }
    for (; j < j1; ++j) {
        int s = col[j];
        float2 v = t2[(size_t)s * 64 + lane];
        ax0 += v.x; ay0 += v.y;
    }
    float sx = (ax0 + ax1) + (ax2 + ax3);
    float sy = (ay0 + ay1) + (ay2 + ay3);
    float zx = fmaxf(fmaf(dd, sx, bv.x), 0.f);
    float zy = fmaxf(fmaf(dd, sy, bv.y), 0.f);

    // phase B: wave-private LDS stash (same wave writes then reads -> in-order, no barrier)
    zs[wid][2 * lane]     = zx;
    zs[wid][2 * lane + 1] = zy;
    __builtin_amdgcn_wave_barrier();  // scheduling fence only (no-op in HW)
    float acc0 = 0.f, acc1 = 0.f;
    const float2* Wv = (const float2*)Wn;
#pragma unroll
    for (int k0 = 0; k0 < HID; k0 += 4) {
        float4 zk = *(const float4*)&zs[wid][k0];   // 16B broadcast read
        float2 w0 = Wv[(size_t)(k0 + 0) * 64 + lane];
        float2 w1 = Wv[(size_t)(k0 + 1) * 64 + lane];
        float2 w2 = Wv[(size_t)(k0 + 2) * 64 + lane];
        float2 w3 = Wv[(size_t)(k0 + 3) * 64 + lane];
        acc0 = fmaf(zk.x, w0.x, acc0); acc1 = fmaf(zk.x, w0.y, acc1);
        acc0 = fmaf(zk.y, w1.x, acc0); acc1 = fmaf(zk.y, w1.y, acc1);
        acc0 = fmaf(zk.z, w2.x, acc0); acc1 = fmaf(zk.z, w2.y, acc1);
        acc0 = fmaf(zk.w, w3.x, acc0); acc1 = fmaf(zk.w, w3.y, acc1);
    }
    float2 o;
    o.x = dd * acc0;
    o.y = dd * acc1;
    ((float2*)tn)[(size_t)d * 64 + lane] = o;
}

// === fused aggregate + ReLU + mean-pool partial sum (layer 3) ===
__global__ __launch_bounds__(256) void k_agg_pool(const float* __restrict__ t,
                                                  const float* __restrict__ dis,
                                                  const int* __restrict__ row_start,
                                                  const int* __restrict__ col,
                                                  const float* __restrict__ bias,
                                                  const int* __restrict__ batch,
                                                  float* __restrict__ fpsum) {
    int lane = threadIdx.x & 63;
    int wid  = threadIdx.x >> 6;
    int d = blockIdx.x * 4 + wid;
    if (d >= N_NODES) return;
    const float2* t2 = (const float2*)t;
    float2 bv = ((const float2*)bias)[lane];
    float dd = dis[d];
    int j0 = row_start[d], j1 = row_start[d + 1];
    float2 self = t2[(size_t)d * 64 + lane];
    float ax0 = self.x, ay0 = self.y;
    float ax1 = 0.f, ay1 = 0.f, ax2 = 0.f, ay2 = 0.f, ax3 = 0.f, ay3 = 0.f;
    int j = j0;
    for (; j + 3 < j1; j += 4) {
        int s0 = col[j], s1 = col[j + 1], s2 = col[j + 2], s3 = col[j + 3];
        float2 v0 = t2[(size_t)s0 * 64 + lane];
        float2 v1 = t2[(size_t)s1 * 64 + lane];
        float2 v2 = t2[(size_t)s2 * 64 + lane];
        float2 v3 = t2[(size_t)s3 * 64 + lane];
        ax0 += v0.x; ay0 += v0.y;
        ax1 += v1.x; ay1 += v1.y;
        ax2 += v2.x; ay2 += v2.y;
        ax3 += v3.x; ay3 += v3.y;
    }
    for (; j < j1; ++j) {
        int s = col[j];
        float2 v = t2[(size_t)s * 64 + lane];
        ax0 += v.x; ay0 += v.y;
    }
    float sx = (ax0 + ax1) + (ax2 + ax3);
    float sy = (ay0 + ay1) + (ay2 + ay3);
    float zx = fmaxf(fmaf(dd, sx, bv.x), 0.f);
    float zy = fmaxf(fmaf(dd, sy, bv.y), 0.f);
    int g = batch[d];
    atomicAdd(&fpsum[g * HID + 2 * lane], zx);
    atomicAdd(&fpsum[g * HID + 2 * lane + 1], zy);
}

// --- final linear with mean folded in ---
__global__ void k_final(const float* __restrict__ fpsum, const int* __restrict__ gcnt,
                        const float* __restrict__ Wl, const float* __restrict__ bl,
                        float* __restrict__ out) {
    int idx = blockIdx.x * blockDim.x + threadIdx.x;
    if (idx >= N_GRAPHS * N_CLASSES) return;
    int g = idx / N_CLASSES, c = idx % N_CLASSES;
    float inv = 1.0f / (float)max(gcnt[g], 1);
    float acc = bl[c];
    for (int f = 0; f < HID; ++f)
        acc = fmaf(fpsum[g * HID + f] * inv, Wl[f * N_CLASSES + c], acc);
    out[idx] = acc;
}

extern "C" void kernel_launch(void* const* d_in, const int* in_sizes, int n_in,
                              void* d_out, int out_size, void* d_ws, size_t ws_size,
                              hipStream_t stream) {
    const float* x     = (const float*)d_in[0];
    const int*   ei    = (const int*)d_in[1];   // [2, E]: row0 = src, row1 = dst
    const int*   batch = (const int*)d_in[2];
    const float* W1 = (const float*)d_in[3];
    const float* b1 = (const float*)d_in[4];
    const float* W2 = (const float*)d_in[5];
    const float* b2 = (const float*)d_in[6];
    const float* W3 = (const float*)d_in[7];
    const float* b3 = (const float*)d_in[8];
    const float* Wl = (const float*)d_in[9];
    const float* bl = (const float*)d_in[10];
    float* out = (float*)d_out;

    const int N = N_NODES, E = N_EDGES;
    const int* srcp = ei;
    const int* dstp = ei + E;

    char* ws = (char*)d_ws;
    size_t off = 0;
    auto alloc = [&](size_t bytes) -> void* {
        void* p = ws + off;
        off += (bytes + 255) & ~(size_t)255;
        return p;
    };
    // zero-initialized region must be first & contiguous (ws is poisoned 0xAA each call)
    int*   ideg   = (int*)alloc((size_t)N * 4);
    int*   cursor = (int*)alloc((size_t)N * 4);
    float* fpsum  = (float*)alloc((size_t)N_GRAPHS * HID * 4);
    size_t zero_bytes = off;
    int*   gcnt  = (int*)alloc((size_t)N_GRAPHS * 4);
    float* dis   = (float*)alloc((size_t)N * 4);
    int*   rowst = (int*)alloc((size_t)(N + 1) * 4);
    int*   col   = (int*)alloc((size_t)E * 4);
    int*   bsum  = (int*)alloc((size_t)SCAN_BLK * 4);
    int*   boff  = (int*)alloc((size_t)(SCAN_BLK + 1) * 4);
    float* bufA  = (float*)alloc((size_t)N * HID * 4);
    float* bufB  = (float*)alloc((size_t)N * HID * 4);

    hipMemsetAsync(d_ws, 0, zero_bytes, stream);

    const int tpb = 256;
    k_deg<<<(E + tpb - 1) / tpb, tpb, 0, stream>>>(dstp, ideg, E);
    k_scan_part<<<SCAN_BLK, 256, 0, stream>>>(ideg, bsum, dis, N);
    k_scan_bsum<<<1, 256, 0, stream>>>(bsum, boff, SCAN_BLK);
    k_scan_write<<<SCAN_BLK, 256, 0, stream>>>(ideg, boff, rowst, N, SCAN_BLK);
    k_fill<<<(E + tpb - 1) / tpb, tpb, 0, stream>>>(srcp, dstp, rowst, cursor, col, E);
    k_goff<<<1, 256, 0, stream>>>(batch, gcnt, N);

    // layer 1 GEMM  (t1 = dis * x@W1)
    k_gemm_in<<<(N * 32 + tpb - 1) / tpb, tpb, 0, stream>>>(x, W1, dis, bufA, N);
    // layer 1 agg + relu + layer-2 GEMM  (t2 = dis * relu(agg(t1)+b1) @ W2)
    k_agg_gemm<<<(N + 3) / 4, 256, 0, stream>>>(bufA, dis, rowst, col, b1, W2, bufB);
    // layer 2 agg + relu + layer-3 GEMM  (t3 = dis * relu(agg(t2)+b2) @ W3)
    k_agg_gemm<<<(N + 3) / 4, 256, 0, stream>>>(bufB, dis, rowst, col, b2, W3, bufA);
    // layer 3 agg + relu + mean-pool partials
    k_agg_pool<<<(N + 3) / 4, 256, 0, stream>>>(bufA, dis, rowst, col, b3, batch, fpsum);
    // classifier
    k_final<<<(N_GRAPHS * N_CLASSES + tpb - 1) / tpb, tpb, 0, stream>>>(fpsum, gcnt, Wl, bl, out);
}